// Round 1
// baseline (665.985 us; speedup 1.0000x reference)
//
#include <hip/hip_runtime.h>
#include <hip/hip_bf16.h>

typedef __attribute__((ext_vector_type(8))) short s16x8;
typedef __attribute__((ext_vector_type(4))) float f32x4;
typedef unsigned short u16;
typedef unsigned int u32;
typedef unsigned long long u64;

__device__ __forceinline__ u16 f2bf(float x) {
  __hip_bfloat16 h = __float2bfloat16(x);
  return *reinterpret_cast<u16*>(&h);
}

// global -> LDS direct (16B). LDS dest must be wave-uniform base + lane*16.
__device__ __forceinline__ void glds16(const void* g, void* lds) {
  __builtin_amdgcn_global_load_lds(
      (const __attribute__((address_space(1))) u32*)(u64)g,
      (__attribute__((address_space(3))) u32*)(u32)(u64)lds, 16, 0, 0);
}

// ---------- cast f32 -> bf16, 8 elems/thread ----------
__global__ __launch_bounds__(256) void k_cast(const float* __restrict__ in,
                                              u16* __restrict__ out) {
  const int i = (blockIdx.x * 256 + threadIdx.x) * 8;
  float4 a = *(const float4*)(in + i);
  float4 b = *(const float4*)(in + i + 4);
  union { s16x8 v; u16 e[8]; } r;
  r.e[0] = f2bf(a.x); r.e[1] = f2bf(a.y); r.e[2] = f2bf(a.z); r.e[3] = f2bf(a.w);
  r.e[4] = f2bf(b.x); r.e[5] = f2bf(b.y); r.e[6] = f2bf(b.z); r.e[7] = f2bf(b.w);
  *(s16x8*)(out + i) = r.v;
}

// ---------- transpose+cast: in f32 [R][C] -> out bf16 [C][R] ----------
__global__ __launch_bounds__(256) void k_tcast(const float* __restrict__ in,
                                               u16* __restrict__ out,
                                               int R, int C) {
  __shared__ u16 t[64][72];
  const int tid = threadIdx.x;
  const int c0 = blockIdx.x * 64, r0 = blockIdx.y * 64;
#pragma unroll
  for (int it = 0; it < 4; ++it) {
    int c = it * 256 + tid;
    int row = c >> 4, sub = c & 15;
    float4 v = *(const float4*)(in + (u64)(r0 + row) * C + c0 + sub * 4);
    t[sub * 4 + 0][row] = f2bf(v.x);
    t[sub * 4 + 1][row] = f2bf(v.y);
    t[sub * 4 + 2][row] = f2bf(v.z);
    t[sub * 4 + 3][row] = f2bf(v.w);
  }
  __syncthreads();
#pragma unroll
  for (int it = 0; it < 2; ++it) {
    int c = it * 256 + tid;
    int orow = c >> 3, osub = c & 7;
    *(s16x8*)(out + (u64)(c0 + orow) * R + r0 + osub * 8) =
        *(const s16x8*)&t[orow][osub * 8];
  }
}

// ---------- V transpose: KV bf16 [4096][2048] (V at cols 1024..) -> VT [32*64][2048]
__global__ __launch_bounds__(256) void k_vtrans(const u16* __restrict__ kv,
                                                u16* __restrict__ vt) {
  __shared__ u16 t[64][72];
  const int bh = blockIdx.x, tb = blockIdx.y;
  const int b = bh >> 4, h = bh & 15;
  const int tid = threadIdx.x;
  const u16* src = kv + (u64)(b * 2048 + tb * 64) * 2048 + 1024 + h * 64;
#pragma unroll
  for (int it = 0; it < 2; ++it) {
    int c = it * 256 + tid;
    int trow = c >> 3, dsub = c & 7;
    union { s16x8 v; u16 e[8]; } u;
    u.v = *(const s16x8*)(src + (u64)trow * 2048 + dsub * 8);
#pragma unroll
    for (int j = 0; j < 8; ++j) t[dsub * 8 + j][trow] = u.e[j];
  }
  __syncthreads();
  u16* dst = vt + (u64)bh * 64 * 2048 + tb * 64;
#pragma unroll
  for (int it = 0; it < 2; ++it) {
    int c = it * 256 + tid;
    int drow = c >> 3, tsub = c & 7;
    *(s16x8*)(dst + (u64)drow * 2048 + tsub * 8) = *(const s16x8*)&t[drow][tsub * 8];
  }
}

// ---------- GEMM: C[M][N] = A[M][K] @ Bt[N][K]^T, bf16 in, BK=64 ----------
// LDS swizzle (involution, 128B rows): phys = logical ^ ((row&7)<<4).
// MODE 0: bf16 store. MODE 1: f32 store of acc + resid + bias.
template <int TM, int TN, int MODE>
__global__ __launch_bounds__(256) void k_gemm(const u16* __restrict__ A,
                                              const u16* __restrict__ Bt,
                                              void* __restrict__ Cout,
                                              const float* __restrict__ resid,
                                              const float* __restrict__ bias,
                                              int M, int N, int K) {
  constexpr int MR = TM / 32, NR = TN / 32;
  __shared__ u16 smem[(TM + TN) * 64];
  const int tid = threadIdx.x;
  const int lane = tid & 63, w = tid >> 6;
  const int g = lane >> 4, lr = lane & 15;
  const int wm = (w >> 1) * (TM / 2), wn = (w & 1) * (TN / 2);
  const int m0 = blockIdx.y * TM, n0 = blockIdx.x * TN;

  f32x4 acc[MR][NR] = {};
  int roff[2];
  roff[0] = (g * 16) ^ ((lr & 7) << 4);
  roff[1] = (64 + g * 16) ^ ((lr & 7) << 4);

  const int nkt = K >> 6;
  for (int kt = 0; kt < nkt; ++kt) {
    const int k0 = kt << 6;
#pragma unroll
    for (int it = 0; it < (TM + TN) / 32; ++it) {
      int c = it * 256 + tid;
      int p = c * 16;  // phys LDS byte (linear dest for glds)
      const u16* gsrc;
      if (c < TM * 8) {
        int lby = p ^ (((p >> 7) & 7) << 4);  // logical byte (involution)
        gsrc = A + (u64)(m0 + (lby >> 7)) * K + k0 + ((lby >> 4) & 7) * 8;
      } else {
        int pb = p - TM * 128;
        int lby = pb ^ (((pb >> 7) & 7) << 4);
        gsrc = Bt + (u64)(n0 + (lby >> 7)) * K + k0 + ((lby >> 4) & 7) * 8;
      }
      glds16(gsrc, (char*)smem + p);
    }
    __syncthreads();
#pragma unroll
    for (int ks = 0; ks < 2; ++ks) {
      s16x8 a[MR], b[NR];
#pragma unroll
      for (int m = 0; m < MR; ++m)
        a[m] = *(const s16x8*)((const char*)smem + (wm + m * 16 + lr) * 128 + roff[ks]);
#pragma unroll
      for (int n = 0; n < NR; ++n)
        b[n] = *(const s16x8*)((const char*)smem + TM * 128 + (wn + n * 16 + lr) * 128 + roff[ks]);
#pragma unroll
      for (int m = 0; m < MR; ++m)
#pragma unroll
        for (int n = 0; n < NR; ++n)
          acc[m][n] = __builtin_amdgcn_mfma_f32_16x16x32_bf16(a[m], b[n], acc[m][n], 0, 0, 0);
    }
    __syncthreads();
  }

#pragma unroll
  for (int m = 0; m < MR; ++m)
#pragma unroll
    for (int n = 0; n < NR; ++n) {
      const int col = n0 + wn + n * 16 + lr;
#pragma unroll
      for (int r = 0; r < 4; ++r) {
        const int row = m0 + wm + m * 16 + g * 4 + r;
        if constexpr (MODE == 0) {
          ((u16*)Cout)[(u64)row * N + col] = f2bf(acc[m][n][r]);
        } else {
          ((float*)Cout)[(u64)row * N + col] =
              acc[m][n][r] + resid[(u64)row * N + col] + bias[col];
        }
      }
    }
}

// ---------- fused dual cross-attention (flash, K/V direct from L2) ----------
// grid (32 bh, 32 qblk); 4 waves x 16 q-rows; D=64; KV tile 64.
__global__ __launch_bounds__(256) void k_attn(const u16* __restrict__ Q,
                                              const u16* __restrict__ Kta,
                                              const u16* __restrict__ Ktv,
                                              const u16* __restrict__ VTta,
                                              const u16* __restrict__ VTtv,
                                              u16* __restrict__ Out) {
  const int bh = blockIdx.x, qb = blockIdx.y;
  const int b = bh >> 4, h = bh & 15;
  const int tid = threadIdx.x, lane = tid & 63, w = tid >> 6;
  const int g = lane >> 4, lr = lane & 15;
  const int qrow = b * 2048 + qb * 64 + w * 16;
  __shared__ u16 plds[4][16][72];  // per-wave P transpose buffer (144B rows: 2-way, free)

  s16x8 qf[2];
#pragma unroll
  for (int ks = 0; ks < 2; ++ks)
    qf[ks] = *(const s16x8*)(Q + (u64)(qrow + lr) * 1024 + h * 64 + ks * 32 + g * 8);

  f32x4 outf[4] = {};
  const float CEXP = 0.125f * 1.44269504088896f;  // SCALE * log2(e)

  for (int br = 0; br < 2; ++br) {
    const u16* Kp = br ? Ktv : Kta;    // [4096][2048], K half at col h*64
    const u16* VTp = br ? VTtv : VTta; // [bh*64+d][2048]
    float mreg[4], lreg[4];
#pragma unroll
    for (int r = 0; r < 4; ++r) { mreg[r] = -1e30f; lreg[r] = 0.f; }
    f32x4 acco[4] = {};

    for (int t = 0; t < 32; ++t) {
      const int kv0 = t * 64;
      f32x4 s[4];
#pragma unroll
      for (int n = 0; n < 4; ++n) {
        const u16* kb = Kp + (u64)(b * 2048 + kv0 + n * 16 + lr) * 2048 + h * 64 + g * 8;
        s16x8 kf0 = *(const s16x8*)kb;
        s16x8 kf1 = *(const s16x8*)(kb + 32);
        f32x4 z = {};
        z = __builtin_amdgcn_mfma_f32_16x16x32_bf16(qf[0], kf0, z, 0, 0, 0);
        s[n] = __builtin_amdgcn_mfma_f32_16x16x32_bf16(qf[1], kf1, z, 0, 0, 0);
      }
      float pvv[4][4];
#pragma unroll
      for (int r = 0; r < 4; ++r) {
        float v = fmaxf(fmaxf(s[0][r], s[1][r]), fmaxf(s[2][r], s[3][r]));
#pragma unroll
        for (int x = 1; x < 16; x <<= 1) v = fmaxf(v, __shfl_xor(v, x));
        float mn = fmaxf(mreg[r], v);
        float corr = __builtin_amdgcn_exp2f((mreg[r] - mn) * CEXP);
        mreg[r] = mn;
        float su = 0.f;
#pragma unroll
        for (int n = 0; n < 4; ++n) {
          float p = __builtin_amdgcn_exp2f((s[n][r] - mn) * CEXP);
          pvv[n][r] = p; su += p;
        }
#pragma unroll
        for (int x = 1; x < 16; x <<= 1) su += __shfl_xor(su, x);
        lreg[r] = lreg[r] * corr + su;
#pragma unroll
        for (int n = 0; n < 4; ++n) acco[n][r] *= corr;
      }
      // C-layout -> A-layout transpose of P through LDS (per-wave, no barrier)
#pragma unroll
      for (int n = 0; n < 4; ++n)
#pragma unroll
        for (int r = 0; r < 4; ++r)
          plds[w][g * 4 + r][n * 16 + lr] = f2bf(pvv[n][r]);
      s16x8 pa[2];
#pragma unroll
      for (int ks = 0; ks < 2; ++ks)
        pa[ks] = *(const s16x8*)&plds[w][lr][ks * 32 + g * 8];
#pragma unroll
      for (int n = 0; n < 4; ++n) {
        const u16* vb = VTp + (u64)(bh * 64 + n * 16 + lr) * 2048 + kv0 + g * 8;
        s16x8 v0 = *(const s16x8*)vb;
        s16x8 v1 = *(const s16x8*)(vb + 32);
        acco[n] = __builtin_amdgcn_mfma_f32_16x16x32_bf16(pa[0], v0, acco[n], 0, 0, 0);
        acco[n] = __builtin_amdgcn_mfma_f32_16x16x32_bf16(pa[1], v1, acco[n], 0, 0, 0);
      }
    }
#pragma unroll
    for (int r = 0; r < 4; ++r) {
      float inv = 1.0f / lreg[r];
#pragma unroll
      for (int n = 0; n < 4; ++n) outf[n][r] += acco[n][r] * inv;
    }
  }
#pragma unroll
  for (int n = 0; n < 4; ++n)
#pragma unroll
    for (int r = 0; r < 4; ++r)
      Out[(u64)(qrow + g * 4 + r) * 1024 + h * 64 + n * 16 + lr] = f2bf(outf[n][r]);
}

extern "C" void kernel_launch(void* const* d_in, const int* in_sizes, int n_in,
                              void* d_out, int out_size, void* d_ws, size_t ws_size,
                              hipStream_t stream) {
  (void)in_sizes; (void)n_in; (void)out_size; (void)ws_size;
  const float* h_t    = (const float*)d_in[0];
  const float* h_a    = (const float*)d_in[1];
  const float* h_v    = (const float*)d_in[2];
  const float* W_q    = (const float*)d_in[3];
  const float* W_k_ta = (const float*)d_in[4];
  const float* W_k_tv = (const float*)d_in[5];
  const float* W_v_ta = (const float*)d_in[6];
  const float* W_v_tv = (const float*)d_in[7];
  const float* W_out  = (const float*)d_in[8];
  const float* b_out  = (const float*)d_in[9];
  float* out = (float*)d_out;

  // workspace layout (u16 elements), total ~136 MiB
  u16* ws    = (u16*)d_ws;
  u16* hT    = ws;                    // [4096][2048]
  u16* hA    = hT + 8388608;
  u16* hV    = hA + 8388608;
  u16* WqT   = hV + 8388608;          // [1024][2048]
  u16* WkvTa = WqT + 2097152;         // [2048][2048]  rows: 0..1023 K^T, 1024.. V^T
  u16* WkvTv = WkvTa + 4194304;
  u16* WoT   = WkvTv + 4194304;       // [2048][1024]
  u16* Qb    = WoT + 2097152;         // [4096][1024]
  u16* KVta  = Qb + 4194304;          // [4096][2048]  cols 0..1023 = K, 1024.. = V
  u16* KVtv  = KVta + 8388608;
  u16* VTta  = KVtv + 8388608;        // [32*64][2048]
  u16* VTtv  = VTta + 4194304;
  u16* AO    = VTtv + 4194304;        // [4096][1024]

  k_cast<<<4096, 256, 0, stream>>>(h_t, hT);
  k_cast<<<4096, 256, 0, stream>>>(h_a, hA);
  k_cast<<<4096, 256, 0, stream>>>(h_v, hV);

  dim3 g1(16, 32);  // for [2048][1024] weights
  k_tcast<<<g1, 256, 0, stream>>>(W_q,    WqT,                2048, 1024);
  k_tcast<<<g1, 256, 0, stream>>>(W_k_ta, WkvTa,              2048, 1024);
  k_tcast<<<g1, 256, 0, stream>>>(W_v_ta, WkvTa + 1024 * 2048, 2048, 1024);
  k_tcast<<<g1, 256, 0, stream>>>(W_k_tv, WkvTv,              2048, 1024);
  k_tcast<<<g1, 256, 0, stream>>>(W_v_tv, WkvTv + 1024 * 2048, 2048, 1024);
  dim3 g2(32, 16);
  k_tcast<<<g2, 256, 0, stream>>>(W_out, WoT, 1024, 2048);

  k_gemm<64, 128, 0><<<dim3(8, 64), 256, 0, stream>>>(hT, WqT, Qb, nullptr, nullptr, 4096, 1024, 2048);
  k_gemm<128, 128, 0><<<dim3(16, 32), 256, 0, stream>>>(hA, WkvTa, KVta, nullptr, nullptr, 4096, 2048, 2048);
  k_gemm<128, 128, 0><<<dim3(16, 32), 256, 0, stream>>>(hV, WkvTv, KVtv, nullptr, nullptr, 4096, 2048, 2048);

  k_vtrans<<<dim3(32, 32), 256, 0, stream>>>(KVta, VTta);
  k_vtrans<<<dim3(32, 32), 256, 0, stream>>>(KVtv, VTtv);

  k_attn<<<dim3(32, 32), 256, 0, stream>>>(Qb, KVta, KVtv, VTta, VTtv, AO);

  k_gemm<128, 128, 1><<<dim3(16, 32), 256, 0, stream>>>(AO, WoT, out, h_t, b_out, 4096, 2048, 1024);
}